// Round 12
// baseline (104.985 us; speedup 1.0000x reference)
//
#include <hip/hip_runtime.h>
#include <hip/hip_bf16.h>

typedef unsigned short u16;
typedef unsigned int u32;
typedef unsigned char u8;
typedef __attribute__((ext_vector_type(4))) int i32x4;
typedef __attribute__((ext_vector_type(16))) int i32x16;

#define MM 4096
#define NN 4096
#define KK 4096   // K in elements == bytes for int8

#define BAR __builtin_amdgcn_s_barrier()
#define FENCE asm volatile("" ::: "memory")
#define WAITVM(n) asm volatile("s_waitcnt vmcnt(" #n ")" ::: "memory")

// LDS (bytes): A0 @0, B0 @16384, A1 @32768, B1 @49152; halves +8192
#define ABUF(sh, b) ((sh) + (b) * 32768)
#define BBUF(sh, b) ((sh) + 16384 + (b) * 32768)

// ---- W: int32 -> packed int8 ----------------------------------------------
__global__ __launch_bounds__(256) void cvt_w_k(const int* __restrict__ w,
                                               u8* __restrict__ o) {
  int i = blockIdx.x * 256 + threadIdx.x;     // 16 int8 per thread
  const int4* w4 = (const int4*)w + (size_t)i * 4;
  i32x4 r;
#pragma unroll
  for (int j = 0; j < 4; ++j) {
    int4 v = w4[j];
    r[j] = (v.x & 255) | ((v.y & 255) << 8) | ((v.z & 255) << 16) | ((u32)(v.w & 255) << 24);
  }
  *(i32x4*)(o + (size_t)i * 16) = r;
}

// ---- A: fp32 -> int8 with per-row symmetric scale (one block per row) ------
__global__ __launch_bounds__(256) void cvt_a_k(const float* __restrict__ x,
                                               u8* __restrict__ o,
                                               float* __restrict__ dA) {
  const int row = blockIdx.x;
  const float4* xr = (const float4*)(x + (size_t)row * KK);
  const int t = threadIdx.x;
  float4 v[4];
  float mx = 0.f;
#pragma unroll
  for (int j = 0; j < 4; ++j) {
    v[j] = xr[t + j * 256];
    mx = fmaxf(mx, fmaxf(fmaxf(fabsf(v[j].x), fabsf(v[j].y)),
                         fmaxf(fabsf(v[j].z), fabsf(v[j].w))));
  }
#pragma unroll
  for (int off = 32; off; off >>= 1) mx = fmaxf(mx, __shfl_down(mx, off));
  __shared__ float sm[4];
  if ((t & 63) == 0) sm[t >> 6] = mx;
  __syncthreads();
  mx = fmaxf(fmaxf(sm[0], sm[1]), fmaxf(sm[2], sm[3]));
  mx = fmaxf(mx, 1e-20f);
  const float inv = 127.0f / mx;
  if (t == 0) dA[row] = mx / 127.0f;
  u32* orow = (u32*)(o + (size_t)row * KK);
#pragma unroll
  for (int j = 0; j < 4; ++j) {
    int qx = (int)rintf(v[j].x * inv), qy = (int)rintf(v[j].y * inv);
    int qz = (int)rintf(v[j].z * inv), qw = (int)rintf(v[j].w * inv);
    orow[t + j * 256] =
        (qx & 255) | ((qy & 255) << 8) | ((qz & 255) << 16) | ((u32)(qw & 255) << 24);
  }
}

// ---- async global->LDS, width 16 ------------------------------------------
__device__ __forceinline__ void gload16(const u8* g, u8* l) {
  __builtin_amdgcn_global_load_lds(
      (const __attribute__((address_space(1))) void*)g,
      (__attribute__((address_space(3))) void*)l, 16, 0, 0);
}

// Stage one half-tile (128 rows x 64 B) = 8 KB; ONE gload16 per thread (512T).
// LDS dest linear; swizzle via permuted global source chunk.
__device__ __forceinline__ void stage_half(const u8* __restrict__ gRowBase,
                                           int k0, u8* ldsHalf, int tid) {
  int row = tid >> 2;                        // 4 x16B chunks per 64B row
  int c = (tid & 3) ^ ((row >> 1) & 3);
  gload16(gRowBase + (size_t)row * KK + k0 + c * 16, ldsHalf + tid * 16);
}

// Swizzled read of one 16B i8 fragment at logical (row r, 16B-chunk q).
__device__ __forceinline__ i32x4 ldsfrag(const u8* base, int r, int q) {
  return *(const i32x4*)(base + r * 64 + (((q ^ (r >> 1)) & 3) << 4));
}

#define MFMAI8(a, b, c) __builtin_amdgcn_mfma_i32_32x32x32_i8(a, b, c, 0, 0, 0)

// ---- 256x256 tile, BK=64, 32x32x32 MFMA, 4 regions/tile ---------------------
// Wave tile 128x64 = 4(mm) x 2(nn) subtiles of 32x32; BK=64 = 2 K-steps (ks).
// Frags: aF0 = mm{0,1}, aF1 = mm{2,3} (4 reads each); bF0/bF1 = nn 0/1 (2 each).
// MFMA groups (4 instr each): G1=aF0xbF0, G2=aF0xbF1, G3=aF1xbF0, G4=aF1xbF1.
// Reads one region ahead (r9 choreography, unchanged):
//   R1: read bF1(t) | R2: read aF1(t), stage B(t+2), WAITVM(2)
//   R3: read aF0(t+1), stage A(t+2) | R4: read bF0(t+1)
template <int MODE>  // 0 = steady (t<=61), 1 = t==62, 2 = t==63
__device__ __forceinline__ void do_tile(
    int t, i32x16 (&acc)[4][2], const u8* Ag, const u8* Wg, u8* sh,
    int tid, int l31, int l5, int wr, int wc,
    i32x4 (&aF0)[4], i32x4 (&aF1)[4], i32x4 (&bF0)[2], i32x4 (&bF1)[2]) {
  const int b = t & 1;
  u8* Acur = ABUF(sh, b);
  u8* Anxt = ABUF(sh, b ^ 1);
  u8* Bcur = BBUF(sh, b);
  u8* Bnxt = BBUF(sh, b ^ 1);

  // ---- R1: read bF1(t); MFMA G1 = aF0 x bF0
#pragma unroll
  for (int ks = 0; ks < 2; ++ks)
    bF1[ks] = ldsfrag(Bcur, wc * 64 + 32 + l31, ks * 2 + l5);
  __builtin_amdgcn_s_setprio(1);
#pragma unroll
  for (int mm = 0; mm < 2; ++mm)
#pragma unroll
    for (int ks = 0; ks < 2; ++ks)
      acc[mm][0] = MFMAI8(aF0[mm * 2 + ks], bF0[ks], acc[mm][0]);
  __builtin_amdgcn_s_setprio(0);
  FENCE; BAR;

  // ---- R2: read aF1(t); stage B(t+2); MFMA G2 = aF0 x bF1; WAITVM
#pragma unroll
  for (int mm = 0; mm < 2; ++mm)
#pragma unroll
    for (int ks = 0; ks < 2; ++ks)
      aF1[mm * 2 + ks] = ldsfrag(Acur, wr * 128 + (2 + mm) * 32 + l31, ks * 2 + l5);
  if (MODE == 0) {
    stage_half(Wg,            (t + 2) * 64, Bcur,        tid);
    stage_half(Wg + 128 * KK, (t + 2) * 64, Bcur + 8192, tid);
  }
  __builtin_amdgcn_s_setprio(1);
#pragma unroll
  for (int mm = 0; mm < 2; ++mm)
#pragma unroll
    for (int ks = 0; ks < 2; ++ks)
      acc[mm][1] = MFMAI8(aF0[mm * 2 + ks], bF1[ks], acc[mm][1]);
  __builtin_amdgcn_s_setprio(0);
  if (MODE == 0) { WAITVM(2); } else if (MODE == 1) { WAITVM(0); }
  FENCE; BAR;

  // ---- R3: read aF0(t+1); stage A(t+2); MFMA G3 = aF1 x bF0
  if (MODE <= 1) {
#pragma unroll
    for (int mm = 0; mm < 2; ++mm)
#pragma unroll
      for (int ks = 0; ks < 2; ++ks)
        aF0[mm * 2 + ks] = ldsfrag(Anxt, wr * 128 + mm * 32 + l31, ks * 2 + l5);
  }
  if (MODE == 0) {
    stage_half(Ag,            (t + 2) * 64, Acur,        tid);
    stage_half(Ag + 128 * KK, (t + 2) * 64, Acur + 8192, tid);
  }
  __builtin_amdgcn_s_setprio(1);
#pragma unroll
  for (int mm = 0; mm < 2; ++mm)
#pragma unroll
    for (int ks = 0; ks < 2; ++ks)
      acc[2 + mm][0] = MFMAI8(aF1[mm * 2 + ks], bF0[ks], acc[2 + mm][0]);
  __builtin_amdgcn_s_setprio(0);
  FENCE; BAR;

  // ---- R4: read bF0(t+1); MFMA G4 = aF1 x bF1
  if (MODE <= 1) {
#pragma unroll
    for (int ks = 0; ks < 2; ++ks)
      bF0[ks] = ldsfrag(Bnxt, wc * 64 + l31, ks * 2 + l5);
  }
  __builtin_amdgcn_s_setprio(1);
#pragma unroll
  for (int mm = 0; mm < 2; ++mm)
#pragma unroll
    for (int ks = 0; ks < 2; ++ks)
      acc[2 + mm][1] = MFMAI8(aF1[mm * 2 + ks], bF1[ks], acc[2 + mm][1]);
  __builtin_amdgcn_s_setprio(0);
  FENCE; BAR;
}

__global__ __launch_bounds__(512, 2) void gemm_k(const u8* __restrict__ A,
                                                 const u8* __restrict__ W,
                                                 const float* __restrict__ dA,
                                                 const float* __restrict__ scales,
                                                 const float* __restrict__ bias,
                                                 float* __restrict__ out) {
  __shared__ u8 sh[65536];  // 64 KiB

  // T1: XCD-aware swizzle (nwg = 256)
  const int cpx = gridDim.x >> 3;
  const int wg = (blockIdx.x & 7) * cpx + (blockIdx.x >> 3);
  const int bm = wg >> 4;
  const int bn = wg & 15;

  const int tid = threadIdx.x;
  const int lane = tid & 63;
  const int l31 = lane & 31;
  const int l5 = lane >> 5;
  const int wid = tid >> 6;
  const int wr = wid >> 2;  // 2 (M) x 4 (N) wave grid; wave tile 128x64
  const int wc = wid & 3;

  i32x16 acc[4][2] = {};
  i32x4 aF0[4], aF1[4], bF0[2], bF1[2];

  const u8* Ag = A + (size_t)bm * 256 * KK;
  const u8* Wg = W + (size_t)bn * 256 * KK;

  // ---- prologue: tile0 all 4 halves + tile1 all 4 halves (8 gloads/thread)
  stage_half(Wg,             0, BBUF(sh, 0),        tid);
  stage_half(Wg + 128 * KK,  0, BBUF(sh, 0) + 8192, tid);
  stage_half(Ag,             0, ABUF(sh, 0),        tid);
  stage_half(Ag + 128 * KK,  0, ABUF(sh, 0) + 8192, tid);
  stage_half(Wg,            64, BBUF(sh, 1),        tid);
  stage_half(Wg + 128 * KK, 64, BBUF(sh, 1) + 8192, tid);
  stage_half(Ag,            64, ABUF(sh, 1),        tid);
  stage_half(Ag + 128 * KK, 64, ABUF(sh, 1) + 8192, tid);
  WAITVM(4);  // tile0's 4 halves landed; tile1's 4 in flight
  BAR;
  // prefetch operands for R1(0): aF0(0), bF0(0)
#pragma unroll
  for (int mm = 0; mm < 2; ++mm)
#pragma unroll
    for (int ks = 0; ks < 2; ++ks)
      aF0[mm * 2 + ks] = ldsfrag(ABUF(sh, 0), wr * 128 + mm * 32 + l31, ks * 2 + l5);
#pragma unroll
  for (int ks = 0; ks < 2; ++ks)
    bF0[ks] = ldsfrag(BBUF(sh, 0), wc * 64 + l31, ks * 2 + l5);

  for (int t = 0; t < 62; ++t)
    do_tile<0>(t, acc, Ag, Wg, sh, tid, l31, l5, wr, wc, aF0, aF1, bF0, bF1);
  do_tile<1>(62, acc, Ag, Wg, sh, tid, l31, l5, wr, wc, aF0, aF1, bF0, bF1);
  do_tile<2>(63, acc, Ag, Wg, sh, tid, l31, l5, wr, wc, aF0, aF1, bF0, bF1);

  // ---- epilogue: dequant (dA[row] * scales[col]) + bias, fp32 store
  // 32x32 C/D layout: col = lane&31, row = (reg&3) + 8*(reg>>2) + 4*(lane>>5)
  const int colb = bn * 256 + wc * 64 + l31;
  const int rowbb = bm * 256 + wr * 128 + 4 * l5;
#pragma unroll
  for (int nn = 0; nn < 2; ++nn) {
    const int col = colb + nn * 32;
    const float sc = scales[col];
    const float bi = bias[col];
#pragma unroll
    for (int mm = 0; mm < 4; ++mm) {
      const int rowb = rowbb + mm * 32;
#pragma unroll
      for (int g = 0; g < 4; ++g)
#pragma unroll
        for (int j = 0; j < 4; ++j) {
          const int row = rowb + 8 * g + j;
          out[(size_t)row * NN + col] =
              (float)acc[mm][nn][g * 4 + j] * (dA[row] * sc) + bi;
        }
    }
  }
}

// ---- fallback (ws too small): correct but slow -----------------------------
__global__ __launch_bounds__(256) void fb_k(const float* __restrict__ A,
                                            const int* __restrict__ W,
                                            const float* __restrict__ scales,
                                            const float* __restrict__ bias,
                                            float* __restrict__ out) {
  __shared__ float Arow[KK];
  const int m = blockIdx.y;
  const int n0 = blockIdx.x * 256;
  const int tid = threadIdx.x;
  for (int k = tid; k < KK; k += 256) Arow[k] = A[(size_t)m * KK + k];
  __syncthreads();
  const int n = n0 + tid;
  float acc = 0.f;
  const int* wrp = W + (size_t)n * KK;
  for (int k = 0; k < KK; ++k) acc += Arow[k] * (float)wrp[k];
  out[(size_t)m * NN + n] = acc * scales[n] + bias[n];
}

extern "C" void kernel_launch(void* const* d_in, const int* in_sizes, int n_in,
                              void* d_out, int out_size, void* d_ws, size_t ws_size,
                              hipStream_t stream) {
  const float* input = (const float*)d_in[0];
  const int* w8 = (const int*)d_in[1];
  const float* scales = (const float*)d_in[2];
  const float* bias = (const float*)d_in[3];
  float* out = (float*)d_out;

  const size_t nelem = (size_t)NN * KK;                    // 16,777,216
  const size_t need = 2 * nelem + MM * sizeof(float);      // 32 MiB + 16 KiB

  if (ws_size >= need) {
    u8* Wq = (u8*)d_ws;
    u8* Aq = Wq + nelem;
    float* dA = (float*)(Aq + nelem);
    cvt_w_k<<<4096, 256, 0, stream>>>(w8, Wq);             // 16 i8/thread
    cvt_a_k<<<MM, 256, 0, stream>>>(input, Aq, dA);        // 1 row/block
    gemm_k<<<256, 512, 0, stream>>>(Aq, Wq, dA, scales, bias, out);
  } else {
    dim3 grid(NN / 256, MM);
    fb_k<<<grid, 256, 0, stream>>>(input, w8, scales, bias, out);
  }
}

// Round 13
// 95.645 us; speedup vs baseline: 1.0976x; 1.0976x over previous
//
#include <hip/hip_runtime.h>
#include <hip/hip_bf16.h>

typedef unsigned short u16;
typedef unsigned int u32;
typedef unsigned char u8;
typedef __attribute__((ext_vector_type(4))) int i32x4;

#define MM 4096
#define NN 4096
#define KK 4096   // K in elements == bytes for int8

#define BAR __builtin_amdgcn_s_barrier()
#define FENCE asm volatile("" ::: "memory")
#define WAITVM(n) asm volatile("s_waitcnt vmcnt(" #n ")" ::: "memory")

// LDS (bytes): A0 @0, B0 @16384, A1 @32768, B1 @49152; halves +8192
#define ABUF(sh, b) ((sh) + (b) * 32768)
#define BBUF(sh, b) ((sh) + 16384 + (b) * 32768)

// ---- merged conversion pass -----------------------------------------------
// blocks [0,4096):   W int32 -> packed int8 (16 i8/thread)
// blocks [4096,8192): A fp32 -> int8, per-row symmetric scale (1 row/block)
__global__ __launch_bounds__(256) void cvt_k(const int* __restrict__ w,
                                             u8* __restrict__ ow,
                                             const float* __restrict__ x,
                                             u8* __restrict__ oa,
                                             float* __restrict__ dA) {
  const int bid = blockIdx.x;
  const int t = threadIdx.x;
  if (bid < 4096) {
    int i = bid * 256 + t;
    const int4* w4 = (const int4*)w + (size_t)i * 4;
    i32x4 r;
#pragma unroll
    for (int j = 0; j < 4; ++j) {
      int4 v = w4[j];
      r[j] = (v.x & 255) | ((v.y & 255) << 8) | ((v.z & 255) << 16) |
             ((u32)(v.w & 255) << 24);
    }
    *(i32x4*)(ow + (size_t)i * 16) = r;
  } else {
    const int row = bid - 4096;
    const float4* xr = (const float4*)(x + (size_t)row * KK);
    float4 v[4];
    float mx = 0.f;
#pragma unroll
    for (int j = 0; j < 4; ++j) {
      v[j] = xr[t + j * 256];
      mx = fmaxf(mx, fmaxf(fmaxf(fabsf(v[j].x), fabsf(v[j].y)),
                           fmaxf(fabsf(v[j].z), fabsf(v[j].w))));
    }
#pragma unroll
    for (int off = 32; off; off >>= 1) mx = fmaxf(mx, __shfl_down(mx, off));
    __shared__ float sm[4];
    if ((t & 63) == 0) sm[t >> 6] = mx;
    __syncthreads();
    mx = fmaxf(fmaxf(sm[0], sm[1]), fmaxf(sm[2], sm[3]));
    mx = fmaxf(mx, 1e-20f);
    const float inv = 127.0f / mx;
    if (t == 0) dA[row] = mx / 127.0f;
    u32* orow = (u32*)(oa + (size_t)row * KK);
#pragma unroll
    for (int j = 0; j < 4; ++j) {
      int qx = (int)rintf(v[j].x * inv), qy = (int)rintf(v[j].y * inv);
      int qz = (int)rintf(v[j].z * inv), qw = (int)rintf(v[j].w * inv);
      orow[t + j * 256] =
          (qx & 255) | ((qy & 255) << 8) | ((qz & 255) << 16) | ((u32)(qw & 255) << 24);
    }
  }
}

// ---- async global->LDS, width 16 ------------------------------------------
__device__ __forceinline__ void gload16(const u8* g, u8* l) {
  __builtin_amdgcn_global_load_lds(
      (const __attribute__((address_space(1))) void*)g,
      (__attribute__((address_space(3))) void*)l, 16, 0, 0);
}

// Stage one half-tile (128 rows x 64 B) = 8 KB; ONE gload16 per thread (512T).
// LDS dest linear; swizzle via permuted global source chunk.
__device__ __forceinline__ void stage_half(const u8* __restrict__ gRowBase,
                                           int k0, u8* ldsHalf, int tid) {
  int row = tid >> 2;                        // 4 x16B chunks per 64B row
  int c = (tid & 3) ^ ((row >> 1) & 3);
  gload16(gRowBase + (size_t)row * KK + k0 + c * 16, ldsHalf + tid * 16);
}

// Swizzled read of one 16B i8 fragment at logical (row r, 16B-chunk q).
__device__ __forceinline__ i32x4 ldsfrag(const u8* base, int r, int q) {
  return *(const i32x4*)(base + r * 64 + (((q ^ (r >> 1)) & 3) << 4));
}

#define MFMAI8(a, b, c) __builtin_amdgcn_mfma_i32_16x16x64_i8(a, b, c, 0, 0, 0)

// ---- 256x256 tile, BK=64, 4 regions/tile, reads one region ahead, ----------
// ---- 2 barriers/tile (end-R1, end-R2 only; end-R3/R4 proved hazard-free) ---
// Reads:  R1: bfr23(t) | R2: afr1(t) | R3: afr0(t+1) | R4: bfr01(t+1)
// Stages: R2: B0,B1(t+2) | R3: A0,A1(t+2)
// Queue:  enter tile with 4 = {B,A}(t+1); R2 +2 -> 6; WAITVM(2) drains (t+1);
//         R3 +2 -> 4. Prologue WAITVM(4). t62 WAITVM(0).
// Hazards covered: end-R1 bar orders last B(t) reads (R4(t-1),R1(t)) before
// R2's B staging; end-R2 bar orders last A(t) reads (R3(t-1),R2(t)) before
// R3's A staging AND publishes landed {B,A}(t+1) for R3/R4/next-R1 reads.
template <int MODE>  // 0 = steady (t<=61), 1 = t==62, 2 = t==63
__device__ __forceinline__ void do_tile(
    int t, i32x4 (&acc)[8][4], const u8* Ag, const u8* Wg, u8* sh,
    int tid, int lr, int hi, int wr, int wc,
    i32x4 (&afr0)[4], i32x4 (&afr1)[4], i32x4 (&bfr01)[2], i32x4 (&bfr23)[2]) {
  const int b = t & 1;
  u8* Acur = ABUF(sh, b);
  u8* Anxt = ABUF(sh, b ^ 1);
  u8* Bcur = BBUF(sh, b);
  u8* Bnxt = BBUF(sh, b ^ 1);

  // ---- R1: read bfr23(t); MFMA P1 = afr0 x bfr01
#pragma unroll
  for (int n = 0; n < 2; ++n)
    bfr23[n] = ldsfrag(Bcur, wc * 64 + (2 + n) * 16 + lr, hi);
  __builtin_amdgcn_s_setprio(1);
#pragma unroll
  for (int m = 0; m < 4; ++m)
#pragma unroll
    for (int n = 0; n < 2; ++n)
      acc[m][n] = MFMAI8(afr0[m], bfr01[n], acc[m][n]);
  __builtin_amdgcn_s_setprio(0);
  FENCE; BAR;  // end-R1: B(t) fully read; B staging may overwrite

  // ---- R2: read afr1(t); stage B(t+2); MFMA P2 = afr0 x bfr23; WAITVM
#pragma unroll
  for (int m = 0; m < 4; ++m)
    afr1[m] = ldsfrag(Acur, wr * 128 + 64 + m * 16 + lr, hi);
  if (MODE == 0) {
    stage_half(Wg,            (t + 2) * 64, Bcur,        tid);
    stage_half(Wg + 128 * KK, (t + 2) * 64, Bcur + 8192, tid);
  }
  __builtin_amdgcn_s_setprio(1);
#pragma unroll
  for (int m = 0; m < 4; ++m)
#pragma unroll
    for (int n = 0; n < 2; ++n)
      acc[m][2 + n] = MFMAI8(afr0[m], bfr23[n], acc[m][2 + n]);
  __builtin_amdgcn_s_setprio(0);
  if (MODE == 0) { WAITVM(2); } else if (MODE == 1) { WAITVM(0); }
  FENCE; BAR;  // end-R2: A(t) fully read; {B,A}(t+1) landed+published

  // ---- R3: read afr0(t+1); stage A(t+2); MFMA P3 = afr1 x bfr01  [no bar]
  if (MODE <= 1) {
#pragma unroll
    for (int m = 0; m < 4; ++m)
      afr0[m] = ldsfrag(Anxt, wr * 128 + m * 16 + lr, hi);
  }
  if (MODE == 0) {
    stage_half(Ag,            (t + 2) * 64, Acur,        tid);
    stage_half(Ag + 128 * KK, (t + 2) * 64, Acur + 8192, tid);
  }
  __builtin_amdgcn_s_setprio(1);
#pragma unroll
  for (int m = 0; m < 4; ++m)
#pragma unroll
    for (int n = 0; n < 2; ++n)
      acc[4 + m][n] = MFMAI8(afr1[m], bfr01[n], acc[4 + m][n]);
  __builtin_amdgcn_s_setprio(0);

  // ---- R4: read bfr01(t+1); MFMA P4 = afr1 x bfr23              [no bar]
  if (MODE <= 1) {
#pragma unroll
    for (int n = 0; n < 2; ++n)
      bfr01[n] = ldsfrag(Bnxt, wc * 64 + n * 16 + lr, hi);
  }
  __builtin_amdgcn_s_setprio(1);
#pragma unroll
  for (int m = 0; m < 4; ++m)
#pragma unroll
    for (int n = 0; n < 2; ++n)
      acc[4 + m][2 + n] = MFMAI8(afr1[m], bfr23[n], acc[4 + m][2 + n]);
  __builtin_amdgcn_s_setprio(0);
}

__global__ __launch_bounds__(512, 2) void gemm_k(const u8* __restrict__ A,
                                                 const u8* __restrict__ W,
                                                 const float* __restrict__ dA,
                                                 const float* __restrict__ scales,
                                                 const float* __restrict__ bias,
                                                 float* __restrict__ out) {
  __shared__ u8 sh[65536];  // 64 KiB

  // T1: XCD-aware swizzle (nwg = 256)
  const int cpx = gridDim.x >> 3;
  const int wg = (blockIdx.x & 7) * cpx + (blockIdx.x >> 3);
  const int bm = wg >> 4;
  const int bn = wg & 15;

  const int tid = threadIdx.x;
  const int lane = tid & 63;
  const int lr = lane & 15;
  const int hi = lane >> 4;
  const int wid = tid >> 6;
  const int wr = wid >> 2;  // 2 (M) x 4 (N) wave grid; wave tile 128x64
  const int wc = wid & 3;

  i32x4 acc[8][4] = {};
  i32x4 afr0[4], afr1[4], bfr01[2], bfr23[2];

  const u8* Ag = A + (size_t)bm * 256 * KK;
  const u8* Wg = W + (size_t)bn * 256 * KK;

  // ---- prologue: tile0 all 4 halves + tile1 all 4 halves (8 gloads/thread)
  stage_half(Wg,             0, BBUF(sh, 0),        tid);
  stage_half(Wg + 128 * KK,  0, BBUF(sh, 0) + 8192, tid);
  stage_half(Ag,             0, ABUF(sh, 0),        tid);
  stage_half(Ag + 128 * KK,  0, ABUF(sh, 0) + 8192, tid);
  stage_half(Wg,            64, BBUF(sh, 1),        tid);
  stage_half(Wg + 128 * KK, 64, BBUF(sh, 1) + 8192, tid);
  stage_half(Ag,            64, ABUF(sh, 1),        tid);
  stage_half(Ag + 128 * KK, 64, ABUF(sh, 1) + 8192, tid);
  WAITVM(4);  // tile0's 4 halves landed; tile1's 4 in flight
  BAR;
  // prefetch operands for R1(0)
#pragma unroll
  for (int m = 0; m < 4; ++m)
    afr0[m] = ldsfrag(ABUF(sh, 0), wr * 128 + m * 16 + lr, hi);
#pragma unroll
  for (int n = 0; n < 2; ++n)
    bfr01[n] = ldsfrag(BBUF(sh, 0), wc * 64 + n * 16 + lr, hi);

  for (int t = 0; t < 62; ++t)
    do_tile<0>(t, acc, Ag, Wg, sh, tid, lr, hi, wr, wc, afr0, afr1, bfr01, bfr23);
  do_tile<1>(62, acc, Ag, Wg, sh, tid, lr, hi, wr, wc, afr0, afr1, bfr01, bfr23);
  do_tile<2>(63, acc, Ag, Wg, sh, tid, lr, hi, wr, wc, afr0, afr1, bfr01, bfr23);

  // ---- epilogue: dequant (dA[row] * scales[col]) + bias, fp32 store
  // C/D layout: col = lane&15, row = (lane>>4)*4 + reg
  const int colb = bn * 256 + wc * 64 + lr;
  const int rowb0 = bm * 256 + wr * 128 + (hi << 2);
#pragma unroll
  for (int m = 0; m < 8; ++m) {
    const int row = rowb0 + m * 16;
    const float da0 = dA[row], da1 = dA[row + 1], da2 = dA[row + 2], da3 = dA[row + 3];
#pragma unroll
    for (int n = 0; n < 4; ++n) {
      const int col = colb + n * 16;
      const float sc = scales[col];
      const float bi = bias[col];
      out[(size_t)(row + 0) * NN + col] = (float)acc[m][n][0] * (da0 * sc) + bi;
      out[(size_t)(row + 1) * NN + col] = (float)acc[m][n][1] * (da1 * sc) + bi;
      out[(size_t)(row + 2) * NN + col] = (float)acc[m][n][2] * (da2 * sc) + bi;
      out[(size_t)(row + 3) * NN + col] = (float)acc[m][n][3] * (da3 * sc) + bi;
    }
  }
}

// ---- fallback (ws too small): correct but slow -----------------------------
__global__ __launch_bounds__(256) void fb_k(const float* __restrict__ A,
                                            const int* __restrict__ W,
                                            const float* __restrict__ scales,
                                            const float* __restrict__ bias,
                                            float* __restrict__ out) {
  __shared__ float Arow[KK];
  const int m = blockIdx.y;
  const int n0 = blockIdx.x * 256;
  const int tid = threadIdx.x;
  for (int k = tid; k < KK; k += 256) Arow[k] = A[(size_t)m * KK + k];
  __syncthreads();
  const int n = n0 + tid;
  float acc = 0.f;
  const int* wrp = W + (size_t)n * KK;
  for (int k = 0; k < KK; ++k) acc += Arow[k] * (float)wrp[k];
  out[(size_t)m * NN + n] = acc * scales[n] + bias[n];
}

extern "C" void kernel_launch(void* const* d_in, const int* in_sizes, int n_in,
                              void* d_out, int out_size, void* d_ws, size_t ws_size,
                              hipStream_t stream) {
  const float* input = (const float*)d_in[0];
  const int* w8 = (const int*)d_in[1];
  const float* scales = (const float*)d_in[2];
  const float* bias = (const float*)d_in[3];
  float* out = (float*)d_out;

  const size_t nelem = (size_t)NN * KK;                    // 16,777,216
  const size_t need = 2 * nelem + MM * sizeof(float);      // 32 MiB + 16 KiB

  if (ws_size >= need) {
    u8* Wq = (u8*)d_ws;
    u8* Aq = Wq + nelem;
    float* dA = (float*)(Aq + nelem);
    cvt_k<<<8192, 256, 0, stream>>>(w8, Wq, input, Aq, dA);
    gemm_k<<<256, 512, 0, stream>>>(Aq, Wq, dA, scales, bias, out);
  } else {
    dim3 grid(NN / 256, MM);
    fb_k<<<grid, 256, 0, stream>>>(input, w8, scales, bias, out);
  }
}